// Round 3
// baseline (196.811 us; speedup 1.0000x reference)
//
#include <hip/hip_runtime.h>

typedef __attribute__((ext_vector_type(8))) short short8;
typedef __attribute__((ext_vector_type(4))) float floatx4;
typedef __attribute__((ext_vector_type(4))) unsigned int uint4v;

#define S_LEN 2048
#define NH 12
#define HD 64
#define EMB 768
#define E3 2304

#define MF(a, b, c) __builtin_amdgcn_mfma_f32_16x16x32_bf16(a, b, c, 0, 0, 0)

__device__ __forceinline__ unsigned short f2bf(float f) {
    unsigned int u = __builtin_bit_cast(unsigned int, f);
    u += 0x7FFFu + ((u >> 16) & 1u);   // RNE
    return (unsigned short)(u >> 16);
}

__device__ __forceinline__ unsigned int pack2bf(float a, float b) {
#if __has_builtin(__builtin_amdgcn_cvt_pk_bf16_f32)
    typedef __attribute__((ext_vector_type(2))) short short2v;
    short2v r = __builtin_amdgcn_cvt_pk_bf16_f32(a, b);
    return __builtin_bit_cast(unsigned int, r);
#else
    return (unsigned int)f2bf(a) | ((unsigned int)f2bf(b) << 16);
#endif
}

// gfx950 cross-quad swaps: vdst[hi]<->vsrc[lo] at 32/16-lane granularity
__device__ __forceinline__ void pl32_swap(unsigned int& x, unsigned int& y) {
#if __has_builtin(__builtin_amdgcn_permlane32_swap)
    typedef __attribute__((ext_vector_type(2))) unsigned int uint2v_;
    uint2v_ r = __builtin_amdgcn_permlane32_swap(x, y, false, false);
    x = r[0]; y = r[1];
#else
    asm("v_permlane32_swap_b32 %0, %1" : "+v"(x), "+v"(y));
#endif
}
__device__ __forceinline__ void pl16_swap(unsigned int& x, unsigned int& y) {
#if __has_builtin(__builtin_amdgcn_permlane16_swap)
    typedef __attribute__((ext_vector_type(2))) unsigned int uint2v_;
    uint2v_ r = __builtin_amdgcn_permlane16_swap(x, y, false, false);
    x = r[0]; y = r[1];
#else
    asm("v_permlane16_swap_b32 %0, %1" : "+v"(x), "+v"(y));
#endif
}

// async global->LDS, 16B/lane; LDS dest = wave-uniform base + lane*16
__device__ __forceinline__ void gl_lds16(const void* g, void* l) {
    __builtin_amdgcn_global_load_lds(
        (const __attribute__((address_space(1))) unsigned int*)g,
        (__attribute__((address_space(3))) unsigned int*)l, 16, 0, 0);
}

// ------------- fused input conversion: x->bf16, W->Wt bf16 -------------------
__global__ __launch_bounds__(256) void conv_fused(const float* __restrict__ x,
                                                  ushort* __restrict__ xb,
                                                  const float* __restrict__ W,
                                                  ushort* __restrict__ Wt) {
    int tid = threadIdx.x;
    if (blockIdx.x < 6144) {                      // x: 8192*768 / 4 per thread
        int i = (blockIdx.x * 256 + tid) * 4;
        float4 f = *(const float4*)(x + i);
        ushort4 o;
        o.x = f2bf(f.x); o.y = f2bf(f.y); o.z = f2bf(f.z); o.w = f2bf(f.w);
        *(ushort4*)(xb + i) = o;
    } else {                                      // W transpose: 72 x 24 tiles of 32x32
        __shared__ float tile[32][33];
        int b2 = blockIdx.x - 6144;
        int n0 = (b2 % 72) * 32, k0 = (b2 / 72) * 32;
        int tx = tid & 31, ty = tid >> 5;
        for (int i = 0; i < 4; i++)
            tile[ty + i * 8][tx] = W[(size_t)(k0 + ty + i * 8) * E3 + n0 + tx];
        __syncthreads();
        for (int i = 0; i < 4; i++)
            Wt[(size_t)(n0 + ty + i * 8) * EMB + k0 + tx] = f2bf(tile[tx][ty + i * 8]);
    }
}

// ---------------- QKV GEMM: [8192,768] x [768,2304] + bias ----------------
// 256x128 tile, 8 waves (4M x 2N), BK=64 (12 K-tiles), 3-deep LDS ring buffer
// (48 KB/tile, 144 KB total, WAR-free: stage t+2 overwrites t-1), 4 phases per
// K-tile with counted vmcnt(6) (never 0 in loop), raw s_barrier, setprio(1)
// around MFMA clusters. XOR-swizzled gl_lds staging (slot cc^row&7).
__global__ __launch_bounds__(512, 1) void qkv_gemm(const ushort* __restrict__ Xb,
                                                   const ushort* __restrict__ Wt,
                                                   const float* __restrict__ bias,
                                                   ushort* __restrict__ QKb,
                                                   ushort* __restrict__ Vt) {
    extern __shared__ char ldsb[];                 // 147456 B dynamic
    const int tid  = threadIdx.x;
    const int w = tid >> 6, lane = tid & 63;
    const int l15 = lane & 15, quad = lane >> 4;
    const int r8 = lane >> 3, cc = lane & 7;
    const int wm = w >> 1, wn = w & 1;             // 4M x 2N wave grid
    const int m0 = blockIdx.x * 256, n0 = blockIdx.y * 128;

    floatx4 acc[4][4] = {};

    // staging sources (bytes); X/Wt row stride = 1536 B; +t*128 per K-tile
    const char* agp = (const char*)Xb + (size_t)(m0 + w * 32 + r8) * 1536 + (cc ^ r8) * 16;
    const char* bgp = (const char*)Wt + (size_t)(n0 + w * 16 + r8) * 1536 + (cc ^ r8) * 16;
    const int adstB = w * 4096;                    // + i*1024 (i<4), A region 32 KB
    const int bdstB = 32768 + w * 2048;            // + i*1024 (i<2), B region 16 KB

    // fragment read addressing (swizzle slot = (kk*4+quad) ^ (row&7))
    const int aroB = (wm * 64 + l15) * 128;        // + mi*2048 + swz[kk]
    const int broB = 32768 + (wn * 64 + l15) * 128;// + ni*2048 + swz[kk]
    const int swz0 = ((quad) ^ (l15 & 7)) * 16;
    const int swz1 = ((4 + quad) ^ (l15 & 7)) * 16;

    // prologue: stage K-tiles 0 and 1 (6 gl_lds insts each)
    for (int i = 0; i < 4; i++) gl_lds16(agp + i * 12288, ldsb + adstB + i * 1024);
    for (int i = 0; i < 2; i++) gl_lds16(bgp + i * 12288, ldsb + bdstB + i * 1024);
    for (int i = 0; i < 4; i++) gl_lds16(agp + 128 + i * 12288, ldsb + 49152 + adstB + i * 1024);
    for (int i = 0; i < 2; i++) gl_lds16(bgp + 128 + i * 12288, ldsb + 49152 + bdstB + i * 1024);

#pragma unroll
    for (int t = 0; t < 12; ++t) {
        // iteration-start wait: K-tile t landed (newest 6 insts = K-tile t+1 may fly)
        if (t < 11) asm volatile("s_waitcnt vmcnt(6)" ::: "memory");
        else        asm volatile("s_waitcnt vmcnt(0)" ::: "memory");
        __builtin_amdgcn_s_barrier();
        __builtin_amdgcn_sched_barrier(0);         // no read hoists above this point

        const char* base = ldsb + (t % 3) * 49152;
        char* sdst = ldsb + ((t + 2) % 3) * 49152; // holds K-tile t-1: reads done
        const int koff = (t + 2) * 128;
        const bool st = (t < 10);

        short8 af0, af1, bf0, bf1, bf2, bf3;

        // ---- phase 0: kk=0, m-half 0 (loads B kk=0) | stage A units 0,1 ----
        af0 = *(const short8*)(base + aroB + 0 * 2048 + swz0);
        af1 = *(const short8*)(base + aroB + 1 * 2048 + swz0);
        bf0 = *(const short8*)(base + broB + 0 * 2048 + swz0);
        bf1 = *(const short8*)(base + broB + 1 * 2048 + swz0);
        bf2 = *(const short8*)(base + broB + 2 * 2048 + swz0);
        bf3 = *(const short8*)(base + broB + 3 * 2048 + swz0);
        if (st) { gl_lds16(agp + koff,         sdst + adstB);
                  gl_lds16(agp + koff + 12288, sdst + adstB + 1024); }
        __builtin_amdgcn_s_setprio(1);
        acc[0][0] = MF(af0, bf0, acc[0][0]); acc[0][1] = MF(af0, bf1, acc[0][1]);
        acc[0][2] = MF(af0, bf2, acc[0][2]); acc[0][3] = MF(af0, bf3, acc[0][3]);
        acc[1][0] = MF(af1, bf0, acc[1][0]); acc[1][1] = MF(af1, bf1, acc[1][1]);
        acc[1][2] = MF(af1, bf2, acc[1][2]); acc[1][3] = MF(af1, bf3, acc[1][3]);
        __builtin_amdgcn_s_setprio(0);
        __builtin_amdgcn_s_barrier();

        // ---- phase 1: kk=0, m-half 1 (reuses B kk=0) | stage A units 2,3 ----
        af0 = *(const short8*)(base + aroB + 2 * 2048 + swz0);
        af1 = *(const short8*)(base + aroB + 3 * 2048 + swz0);
        if (st) { gl_lds16(agp + koff + 2 * 12288, sdst + adstB + 2048);
                  gl_lds16(agp + koff + 3 * 12288, sdst + adstB + 3072); }
        __builtin_amdgcn_s_setprio(1);
        acc[2][0] = MF(af0, bf0, acc[2][0]); acc[2][1] = MF(af0, bf1, acc[2][1]);
        acc[2][2] = MF(af0, bf2, acc[2][2]); acc[2][3] = MF(af0, bf3, acc[2][3]);
        acc[3][0] = MF(af1, bf0, acc[3][0]); acc[3][1] = MF(af1, bf1, acc[3][1]);
        acc[3][2] = MF(af1, bf2, acc[3][2]); acc[3][3] = MF(af1, bf3, acc[3][3]);
        __builtin_amdgcn_s_setprio(0);
        __builtin_amdgcn_s_barrier();

        // ---- phase 2: kk=1, m-half 0 (loads B kk=1) | stage B units 0,1 ----
        af0 = *(const short8*)(base + aroB + 0 * 2048 + swz1);
        af1 = *(const short8*)(base + aroB + 1 * 2048 + swz1);
        bf0 = *(const short8*)(base + broB + 0 * 2048 + swz1);
        bf1 = *(const short8*)(base + broB + 1 * 2048 + swz1);
        bf2 = *(const short8*)(base + broB + 2 * 2048 + swz1);
        bf3 = *(const short8*)(base + broB + 3 * 2048 + swz1);
        if (st) { gl_lds16(bgp + koff,         sdst + bdstB);
                  gl_lds16(bgp + koff + 12288, sdst + bdstB + 1024); }
        __builtin_amdgcn_s_setprio(1);
        acc[0][0] = MF(af0, bf0, acc[0][0]); acc[0][1] = MF(af0, bf1, acc[0][1]);
        acc[0][2] = MF(af0, bf2, acc[0][2]); acc[0][3] = MF(af0, bf3, acc[0][3]);
        acc[1][0] = MF(af1, bf0, acc[1][0]); acc[1][1] = MF(af1, bf1, acc[1][1]);
        acc[1][2] = MF(af1, bf2, acc[1][2]); acc[1][3] = MF(af1, bf3, acc[1][3]);
        __builtin_amdgcn_s_setprio(0);
        __builtin_amdgcn_s_barrier();

        // ---- phase 3: kk=1, m-half 1 (reuses B kk=1) | no stage ----
        af0 = *(const short8*)(base + aroB + 2 * 2048 + swz1);
        af1 = *(const short8*)(base + aroB + 3 * 2048 + swz1);
        __builtin_amdgcn_s_setprio(1);
        acc[2][0] = MF(af0, bf0, acc[2][0]); acc[2][1] = MF(af0, bf1, acc[2][1]);
        acc[2][2] = MF(af0, bf2, acc[2][2]); acc[2][3] = MF(af0, bf3, acc[2][3]);
        acc[3][0] = MF(af1, bf0, acc[3][0]); acc[3][1] = MF(af1, bf1, acc[3][1]);
        acc[3][2] = MF(af1, bf2, acc[3][2]); acc[3][3] = MF(af1, bf3, acc[3][3]);
        __builtin_amdgcn_s_setprio(0);
        // next iteration's start barrier closes this K-tile
    }

    // ---------------- epilogue (LDS reused after full drain) ----------------
    __syncthreads();
    ushort* epi = (ushort*)ldsb;
    int seg = n0 >= 1536 ? 2 : (n0 >= 768 ? 1 : 0);
    if (seg < 2) {
        float scale = (seg == 0) ? 0.125f : 1.0f;   // fold attention scale into Q
        for (int ni = 0; ni < 4; ni++) {
            int nl = wn * 64 + ni * 16 + l15;
            float bv = bias[n0 + nl];
            for (int mi = 0; mi < 4; mi++)
                for (int r = 0; r < 4; r++) {
                    int ml = wm * 64 + mi * 16 + quad * 4 + r;
                    epi[ml * 132 + nl] = f2bf((acc[mi][ni][r] + bv) * scale);
                }
        }
        __syncthreads();
        int row = tid >> 1, h2 = tid & 1;           // 512 threads, 256 rows
        size_t gm = (size_t)(m0 + row);
        for (int i = 0; i < 8; i++) {
            uint4 v = *(const uint4*)&epi[row * 132 + h2 * 64 + i * 8];
            *(uint4*)&QKb[gm * 1536 + n0 + h2 * 64 + i * 8] = v;
        }
    } else {
        for (int ni = 0; ni < 4; ni++) {
            int nl = wn * 64 + ni * 16 + l15;
            float bv = bias[n0 + nl];
            for (int mi = 0; mi < 4; mi++) {
                int ml = wm * 64 + mi * 16 + quad * 4;
                ushort4 p4;
                p4.x = f2bf(acc[mi][ni][0] + bv);
                p4.y = f2bf(acc[mi][ni][1] + bv);
                p4.z = f2bf(acc[mi][ni][2] + bv);
                p4.w = f2bf(acc[mi][ni][3] + bv);
                *(ushort4*)&epi[nl * 264 + ml] = p4;
            }
        }
        __syncthreads();
        int row = tid >> 2, q4 = tid & 3;           // 128 rows x 4 col-quarters
        int nn = n0 + row - 1536;
        int hh = nn >> 6, d = nn & 63;
        int bb = m0 >> 11, s0 = m0 & 2047;          // 256 | 2048 so bb uniform
        for (int i = 0; i < 8; i++) {
            uint4 v = *(const uint4*)&epi[row * 264 + q4 * 64 + i * 8];
            *(uint4*)&Vt[((size_t)(bb * NH + hh) * HD + d) * S_LEN + s0 + q4 * 64 + i * 8] = v;
        }
    }
}

// ---------------- Attention: ReLU(Q K^T, causal) @ V  (Q pre-scaled) --------
// Static balanced schedule (504 blocks), 1 barrier/stage, cross-item K prefetch.
// K staged in LDS (4x wave reuse, XOR-swizzled); V read DIRECTLY from global
// Vt[d][s] (L2-resident, 64B segments/row) -- V staging was pure overhead.
// PV via 16x16x32 with permlane cross-quad repack. setprio around MFMA
// clusters; jsub order staggered by wave parity; fully-masked diag half-stages
// skipped for waves 0-1.
__global__ __launch_bounds__(256, 2) void attn(const ushort* __restrict__ QKb,
                                               const ushort* __restrict__ Vt,
                                               float* __restrict__ out) {
    __shared__ ushort lds[16384];   // 32KB: K double-buffer @0 / @16384B
    char* ldsb = (char*)lds;
    int tid = threadIdx.x;
    int w = tid >> 6, lane = tid & 63;
    int l15 = lane & 15, quad = lane >> 4;
    int r8 = lane >> 3, cc = lane & 7;

    // ---- hoisted lane-dependent offsets (loop-invariant) ----
    int kfo[2];
    for (int ch = 0; ch < 2; ch++)
        kfo[ch] = l15 * 128 + ((ch * 4 + quad) ^ (l15 & 7)) * 16;
    int rhs[2] = { w * 32 + l15, w * 32 + 16 + l15 };   // causal threshold (qt cancels)
    int kgo = (w * 32 + r8) * 3072 + (cc ^ r8) * 16;    // K staging (QKb row = 3072 B)
    int kst = (w * 32) * 128;            // LDS K dst, + i*1024 + p*16384
    // V direct-read lane offset (ushort units): d-row l15 (+ni*16), k-col quad*8
    const int vlo = l15 * S_LEN + quad * 8;

    // ---- static bucket schedule: 504 blocks cover all 768 (qt,bh) items ----
    int b = blockIdx.x;
    int nit, qts[2], bhs[2];
    if (b < 240)      { nit = 1; qts[0] = 15 - b / 48; bhs[0] = b % 48; qts[1] = 0; bhs[1] = 0; }
    else if (b < 480) { int j = b - 240; nit = 2; qts[0] = 10 - j / 48; bhs[0] = j % 48;
                        qts[1] = 1 + j / 48; bhs[1] = j % 48; }
    else              { int j = b - 480; nit = 2; qts[0] = 0; bhs[0] = 2 * j;
                        qts[1] = 0; bhs[1] = 2 * j + 1; }

    const char* kg[2]; const ushort* vb[2];
    for (int i = 0; i < 2; i++) {
        int bh = bhs[i], bg = bh / NH, h = bh % NH;
        kg[i] = (const char*)(QKb + (size_t)bg * S_LEN * 1536 + 768 + h * 64) + kgo;
        vb[i] = Vt + (size_t)bh * HD * S_LEN;
    }

    auto prefK = [&](const char* kbase, int dstP) {
        for (int i = 0; i < 4; i++)
            gl_lds16(kbase + i * 24576, ldsb + dstP * 16384 + kst + i * 1024);
    };

    int p = 0;
    prefK(kg[0], 0);
    for (int ii = 0; ii < nit; ii++) {
        int qt = qts[ii];
        int bh = bhs[ii], bg = bh / NH, h = bh % NH;
        const ushort* Qcol = QKb + (size_t)bg * S_LEN * 1536 + h * 64;
        short8 qf[2][2];
        for (int nq = 0; nq < 2; nq++)
            for (int ch = 0; ch < 2; ch++)
                qf[nq][ch] = *(const short8*)(Qcol +
                    (size_t)(qt * 128 + w * 32 + nq * 16 + l15) * 1536 + ch * 32 + quad * 8);
        // hoisted V row pointers (d-row = ni*16 + l15; + k index per stage)
        const ushort* vp[4];
        for (int ni = 0; ni < 4; ni++)
            vp[ni] = vb[ii] + (size_t)ni * 16 * S_LEN + vlo;

        floatx4 acco[2][4] = {};
        int nst = qt + 1;
        for (int st = 0; st < nst; st++) {
            __syncthreads();                       // sole barrier: K buf[p] staged
            if (st + 1 < nst)
                prefK(kg[ii] + (size_t)(st + 1) * 393216, p ^ 1);
            else if (ii + 1 < nit)
                prefK(kg[ii + 1], p ^ 1);          // next item's stage 0

            bool diag = (st == qt);
            const char* kb = ldsb + p * 16384;
            int k0 = st * 128;

            for (int js = 0; js < 2; js++) {
                int jsub = js ^ (w & 1);           // stagger LDS bursts across waves
                if (diag && w < 2 && jsub == 1) continue;  // fully-masked half

                // V loads issued first: latency hides under QK^T MFMAs
                short8 vf[2][4];
                for (int t2 = 0; t2 < 2; t2++)
                    for (int ni = 0; ni < 4; ni++)
                        vf[t2][ni] = *(const short8*)(vp[ni] + k0 + jsub * 64 + t2 * 32);

                // S^T = K·Q^T : 64 k-rows x 32 q, K(d)=64
                floatx4 stc[4][2] = {};
                __builtin_amdgcn_s_setprio(1);
                for (int ch = 0; ch < 2; ch++) {
                    short8 kf[4];
                    for (int mk = 0; mk < 4; mk++)
                        kf[mk] = *(const short8*)(kb + kfo[ch] + jsub * 8192 + mk * 2048);
                    for (int mk = 0; mk < 4; mk++)
                        for (int nq = 0; nq < 2; nq++)
                            stc[mk][nq] = __builtin_amdgcn_mfma_f32_16x16x32_bf16(
                                kf[mk], qf[nq][ch], stc[mk][nq], 0, 0, 0);
                }
                __builtin_amdgcn_s_setprio(0);

                // ReLU + causal mask + pack (k = quad*4 + r layout, 2 bf16/uint)
                unsigned int pk[4][2][2];
                for (int mk = 0; mk < 4; mk++) {
                    for (int nq = 0; nq < 2; nq++) {
                        float e[4];
                        for (int r = 0; r < 4; r++)
                            e[r] = fmaxf(stc[mk][nq][r], 0.0f);
                        if (diag) {
                            int kl = jsub * 64 + mk * 16 + quad * 4;
                            for (int r = 0; r < 4; r++)
                                if (kl + r > rhs[nq]) e[r] = 0.0f;
                        }
                        pk[mk][nq][0] = pack2bf(e[0], e[1]);
                        pk[mk][nq][1] = pack2bf(e[2], e[3]);
                    }
                }

                // O += P·V via 16x16x32: repack P cross-quad with permlane swaps
                __builtin_amdgcn_s_setprio(1);
                for (int pr = 0; pr < 2; pr++) {
                    for (int mi = 0; mi < 2; mi++) {
                        unsigned int a0 = pk[2 * pr][mi][0], a1 = pk[2 * pr][mi][1];
                        unsigned int b0 = pk[2 * pr + 1][mi][0], b1 = pk[2 * pr + 1][mi][1];
                        pl32_swap(a0, b0);  pl32_swap(a1, b1);
                        pl16_swap(a0, b0);  pl16_swap(a1, b1);
                        // now: a0=k q*8+{0,1}, a1=+{2,3}, b0=+{4,5}, b1=+{6,7}
                        short8 af = __builtin_bit_cast(short8, (uint4v){a0, a1, b0, b1});
                        for (int ni = 0; ni < 4; ni++)
                            acco[mi][ni] = __builtin_amdgcn_mfma_f32_16x16x32_bf16(
                                af, vf[pr][ni], acco[mi][ni], 0, 0, 0);
                    }
                }
                __builtin_amdgcn_s_setprio(0);
            }
            p ^= 1;
        }

        // epilogue: out[b][s][h*64+d] fp32 (overlaps next item's prefetch)
        for (int mi = 0; mi < 2; mi++) {
            for (int ni = 0; ni < 4; ni++) {
                int d = ni * 16 + l15;
                for (int r = 0; r < 4; r++) {
                    int s = qt * 128 + w * 32 + mi * 16 + quad * 4 + r;
                    out[((size_t)bg * S_LEN + s) * EMB + h * 64 + d] = acco[mi][ni][r];
                }
            }
        }
    }
}

extern "C" void kernel_launch(void* const* d_in, const int* in_sizes, int n_in,
                              void* d_out, int out_size, void* d_ws, size_t ws_size,
                              hipStream_t stream) {
    const float* x    = (const float*)d_in[0];   // [4,2048,768]
    const float* W    = (const float*)d_in[1];   // [768,2304]
    const float* bias = (const float*)d_in[2];   // [2304]
    float* out = (float*)d_out;                  // [4,2048,768] fp32

    char* ws = (char*)d_ws;
    const size_t SZ_X  = (size_t)8192 * EMB * 2;
    const size_t SZ_W  = (size_t)E3 * EMB * 2;
    const size_t SZ_QK = (size_t)8192 * 1536 * 2;
    ushort* Xb  = (ushort*)(ws);
    ushort* Wt  = (ushort*)(ws + SZ_X);
    ushort* QKb = (ushort*)(ws + SZ_X + SZ_W);
    ushort* Vt  = (ushort*)(ws + SZ_X + SZ_W + SZ_QK);

    static bool attr_done = false;
    if (!attr_done) {
        hipFuncSetAttribute((const void*)qkv_gemm,
                            hipFuncAttributeMaxDynamicSharedMemorySize, 147456);
        attr_done = true;
    }

    conv_fused<<<dim3(6144 + 1728), dim3(256), 0, stream>>>(x, Xb, W, Wt);
    qkv_gemm<<<dim3(32, 18), dim3(512), 147456, stream>>>(Xb, Wt, bias, QKb, Vt);
    attn<<<dim3(504), dim3(256), 0, stream>>>(QKb, Vt, out);
}

// Round 4
// 189.821 us; speedup vs baseline: 1.0368x; 1.0368x over previous
//
#include <hip/hip_runtime.h>

typedef __attribute__((ext_vector_type(8))) short short8;
typedef __attribute__((ext_vector_type(4))) float floatx4;
typedef __attribute__((ext_vector_type(4))) unsigned int uint4v;

#define S_LEN 2048
#define NH 12
#define HD 64
#define EMB 768
#define E3 2304

#define MF(a, b, c) __builtin_amdgcn_mfma_f32_16x16x32_bf16(a, b, c, 0, 0, 0)

__device__ __forceinline__ unsigned short f2bf(float f) {
    unsigned int u = __builtin_bit_cast(unsigned int, f);
    u += 0x7FFFu + ((u >> 16) & 1u);   // RNE
    return (unsigned short)(u >> 16);
}

__device__ __forceinline__ unsigned int pack2bf(float a, float b) {
#if __has_builtin(__builtin_amdgcn_cvt_pk_bf16_f32)
    typedef __attribute__((ext_vector_type(2))) short short2v;
    short2v r = __builtin_amdgcn_cvt_pk_bf16_f32(a, b);
    return __builtin_bit_cast(unsigned int, r);
#else
    return (unsigned int)f2bf(a) | ((unsigned int)f2bf(b) << 16);
#endif
}

// gfx950 cross-quad swaps: vdst[hi]<->vsrc[lo] at 32/16-lane granularity
__device__ __forceinline__ void pl32_swap(unsigned int& x, unsigned int& y) {
#if __has_builtin(__builtin_amdgcn_permlane32_swap)
    typedef __attribute__((ext_vector_type(2))) unsigned int uint2v_;
    uint2v_ r = __builtin_amdgcn_permlane32_swap(x, y, false, false);
    x = r[0]; y = r[1];
#else
    asm("v_permlane32_swap_b32 %0, %1" : "+v"(x), "+v"(y));
#endif
}
__device__ __forceinline__ void pl16_swap(unsigned int& x, unsigned int& y) {
#if __has_builtin(__builtin_amdgcn_permlane16_swap)
    typedef __attribute__((ext_vector_type(2))) unsigned int uint2v_;
    uint2v_ r = __builtin_amdgcn_permlane16_swap(x, y, false, false);
    x = r[0]; y = r[1];
#else
    asm("v_permlane16_swap_b32 %0, %1" : "+v"(x), "+v"(y));
#endif
}

// async global->LDS, 16B/lane; LDS dest = wave-uniform base + lane*16
__device__ __forceinline__ void gl_lds16(const void* g, void* l) {
    __builtin_amdgcn_global_load_lds(
        (const __attribute__((address_space(1))) unsigned int*)g,
        (__attribute__((address_space(3))) unsigned int*)l, 16, 0, 0);
}

// ------------- fused input conversion: x->bf16, W->Wt bf16 -------------------
__global__ __launch_bounds__(256) void conv_fused(const float* __restrict__ x,
                                                  ushort* __restrict__ xb,
                                                  const float* __restrict__ W,
                                                  ushort* __restrict__ Wt) {
    int tid = threadIdx.x;
    if (blockIdx.x < 6144) {                      // x: 8192*768 / 4 per thread
        int i = (blockIdx.x * 256 + tid) * 4;
        float4 f = *(const float4*)(x + i);
        ushort4 o;
        o.x = f2bf(f.x); o.y = f2bf(f.y); o.z = f2bf(f.z); o.w = f2bf(f.w);
        *(ushort4*)(xb + i) = o;
    } else {                                      // W transpose: 72 x 24 tiles of 32x32
        __shared__ float tile[32][33];
        int b2 = blockIdx.x - 6144;
        int n0 = (b2 % 72) * 32, k0 = (b2 / 72) * 32;
        int tx = tid & 31, ty = tid >> 5;
        for (int i = 0; i < 4; i++)
            tile[ty + i * 8][tx] = W[(size_t)(k0 + ty + i * 8) * E3 + n0 + tx];
        __syncthreads();
        for (int i = 0; i < 4; i++)
            Wt[(size_t)(n0 + ty + i * 8) * EMB + k0 + tx] = f2bf(tile[tx][ty + i * 8]);
    }
}

// ---------------- QKV GEMM: [8192,768] x [768,2304] + bias ----------------
// 256x128 tile, 8 waves (4M x 2N), BK=64 (12 K-tiles), 3-deep LDS ring buffer
// (48 KB/tile, 144 KB total, WAR-free: stage t+2 overwrites t-1), 4 phases per
// K-tile with counted vmcnt(6) (never 0 in loop), raw s_barrier, setprio(1)
// around MFMA clusters. XOR-swizzled gl_lds staging (slot cc^row&7).
__global__ __launch_bounds__(512, 1) void qkv_gemm(const ushort* __restrict__ Xb,
                                                   const ushort* __restrict__ Wt,
                                                   const float* __restrict__ bias,
                                                   ushort* __restrict__ QKb,
                                                   ushort* __restrict__ Vt) {
    extern __shared__ char ldsb[];                 // 147456 B dynamic
    const int tid  = threadIdx.x;
    const int w = tid >> 6, lane = tid & 63;
    const int l15 = lane & 15, quad = lane >> 4;
    const int r8 = lane >> 3, cc = lane & 7;
    const int wm = w >> 1, wn = w & 1;             // 4M x 2N wave grid
    const int m0 = blockIdx.x * 256, n0 = blockIdx.y * 128;

    floatx4 acc[4][4] = {};

    // staging sources (bytes); X/Wt row stride = 1536 B; +t*128 per K-tile
    const char* agp = (const char*)Xb + (size_t)(m0 + w * 32 + r8) * 1536 + (cc ^ r8) * 16;
    const char* bgp = (const char*)Wt + (size_t)(n0 + w * 16 + r8) * 1536 + (cc ^ r8) * 16;
    const int adstB = w * 4096;                    // + i*1024 (i<4), A region 32 KB
    const int bdstB = 32768 + w * 2048;            // + i*1024 (i<2), B region 16 KB

    // fragment read addressing (swizzle slot = (kk*4+quad) ^ (row&7))
    const int aroB = (wm * 64 + l15) * 128;        // + mi*2048 + swz[kk]
    const int broB = 32768 + (wn * 64 + l15) * 128;// + ni*2048 + swz[kk]
    const int swz0 = ((quad) ^ (l15 & 7)) * 16;
    const int swz1 = ((4 + quad) ^ (l15 & 7)) * 16;

    // prologue: stage K-tiles 0 and 1 (6 gl_lds insts each)
    for (int i = 0; i < 4; i++) gl_lds16(agp + i * 12288, ldsb + adstB + i * 1024);
    for (int i = 0; i < 2; i++) gl_lds16(bgp + i * 12288, ldsb + bdstB + i * 1024);
    for (int i = 0; i < 4; i++) gl_lds16(agp + 128 + i * 12288, ldsb + 49152 + adstB + i * 1024);
    for (int i = 0; i < 2; i++) gl_lds16(bgp + 128 + i * 12288, ldsb + 49152 + bdstB + i * 1024);

#pragma unroll
    for (int t = 0; t < 12; ++t) {
        // iteration-start wait: K-tile t landed (newest 6 insts = K-tile t+1 may fly)
        if (t < 11) asm volatile("s_waitcnt vmcnt(6)" ::: "memory");
        else        asm volatile("s_waitcnt vmcnt(0)" ::: "memory");
        __builtin_amdgcn_s_barrier();
        __builtin_amdgcn_sched_barrier(0);         // no read hoists above this point

        const char* base = ldsb + (t % 3) * 49152;
        char* sdst = ldsb + ((t + 2) % 3) * 49152; // holds K-tile t-1: reads done
        const int koff = (t + 2) * 128;
        const bool st = (t < 10);

        short8 af0, af1, bf0, bf1, bf2, bf3;

        // ---- phase 0: kk=0, m-half 0 (loads B kk=0) | stage A units 0,1 ----
        af0 = *(const short8*)(base + aroB + 0 * 2048 + swz0);
        af1 = *(const short8*)(base + aroB + 1 * 2048 + swz0);
        bf0 = *(const short8*)(base + broB + 0 * 2048 + swz0);
        bf1 = *(const short8*)(base + broB + 1 * 2048 + swz0);
        bf2 = *(const short8*)(base + broB + 2 * 2048 + swz0);
        bf3 = *(const short8*)(base + broB + 3 * 2048 + swz0);
        if (st) { gl_lds16(agp + koff,         sdst + adstB);
                  gl_lds16(agp + koff + 12288, sdst + adstB + 1024); }
        __builtin_amdgcn_s_setprio(1);
        acc[0][0] = MF(af0, bf0, acc[0][0]); acc[0][1] = MF(af0, bf1, acc[0][1]);
        acc[0][2] = MF(af0, bf2, acc[0][2]); acc[0][3] = MF(af0, bf3, acc[0][3]);
        acc[1][0] = MF(af1, bf0, acc[1][0]); acc[1][1] = MF(af1, bf1, acc[1][1]);
        acc[1][2] = MF(af1, bf2, acc[1][2]); acc[1][3] = MF(af1, bf3, acc[1][3]);
        __builtin_amdgcn_s_setprio(0);
        __builtin_amdgcn_s_barrier();

        // ---- phase 1: kk=0, m-half 1 (reuses B kk=0) | stage A units 2,3 ----
        af0 = *(const short8*)(base + aroB + 2 * 2048 + swz0);
        af1 = *(const short8*)(base + aroB + 3 * 2048 + swz0);
        if (st) { gl_lds16(agp + koff + 2 * 12288, sdst + adstB + 2048);
                  gl_lds16(agp + koff + 3 * 12288, sdst + adstB + 3072); }
        __builtin_amdgcn_s_setprio(1);
        acc[2][0] = MF(af0, bf0, acc[2][0]); acc[2][1] = MF(af0, bf1, acc[2][1]);
        acc[2][2] = MF(af0, bf2, acc[2][2]); acc[2][3] = MF(af0, bf3, acc[2][3]);
        acc[3][0] = MF(af1, bf0, acc[3][0]); acc[3][1] = MF(af1, bf1, acc[3][1]);
        acc[3][2] = MF(af1, bf2, acc[3][2]); acc[3][3] = MF(af1, bf3, acc[3][3]);
        __builtin_amdgcn_s_setprio(0);
        __builtin_amdgcn_s_barrier();

        // ---- phase 2: kk=1, m-half 0 (loads B kk=1) | stage B units 0,1 ----
        af0 = *(const short8*)(base + aroB + 0 * 2048 + swz1);
        af1 = *(const short8*)(base + aroB + 1 * 2048 + swz1);
        bf0 = *(const short8*)(base + broB + 0 * 2048 + swz1);
        bf1 = *(const short8*)(base + broB + 1 * 2048 + swz1);
        bf2 = *(const short8*)(base + broB + 2 * 2048 + swz1);
        bf3 = *(const short8*)(base + broB + 3 * 2048 + swz1);
        if (st) { gl_lds16(bgp + koff,         sdst + bdstB);
                  gl_lds16(bgp + koff + 12288, sdst + bdstB + 1024); }
        __builtin_amdgcn_s_setprio(1);
        acc[0][0] = MF(af0, bf0, acc[0][0]); acc[0][1] = MF(af0, bf1, acc[0][1]);
        acc[0][2] = MF(af0, bf2, acc[0][2]); acc[0][3] = MF(af0, bf3, acc[0][3]);
        acc[1][0] = MF(af1, bf0, acc[1][0]); acc[1][1] = MF(af1, bf1, acc[1][1]);
        acc[1][2] = MF(af1, bf2, acc[1][2]); acc[1][3] = MF(af1, bf3, acc[1][3]);
        __builtin_amdgcn_s_setprio(0);
        __builtin_amdgcn_s_barrier();

        // ---- phase 3: kk=1, m-half 1 (reuses B kk=1) | no stage ----
        af0 = *(const short8*)(base + aroB + 2 * 2048 + swz1);
        af1 = *(const short8*)(base + aroB + 3 * 2048 + swz1);
        __builtin_amdgcn_s_setprio(1);
        acc[2][0] = MF(af0, bf0, acc[2][0]); acc[2][1] = MF(af0, bf1, acc[2][1]);
        acc[2][2] = MF(af0, bf2, acc[2][2]); acc[2][3] = MF(af0, bf3, acc[2][3]);
        acc[3][0] = MF(af1, bf0, acc[3][0]); acc[3][1] = MF(af1, bf1, acc[3][1]);
        acc[3][2] = MF(af1, bf2, acc[3][2]); acc[3][3] = MF(af1, bf3, acc[3][3]);
        __builtin_amdgcn_s_setprio(0);
        // next iteration's start barrier closes this K-tile
    }

    // ---------------- epilogue (LDS reused after full drain) ----------------
    __syncthreads();
    ushort* epi = (ushort*)ldsb;
    int seg = n0 >= 1536 ? 2 : (n0 >= 768 ? 1 : 0);
    if (seg < 2) {
        float scale = (seg == 0) ? 0.125f : 1.0f;   // fold attention scale into Q
        for (int ni = 0; ni < 4; ni++) {
            int nl = wn * 64 + ni * 16 + l15;
            float bv = bias[n0 + nl];
            for (int mi = 0; mi < 4; mi++)
                for (int r = 0; r < 4; r++) {
                    int ml = wm * 64 + mi * 16 + quad * 4 + r;
                    epi[ml * 132 + nl] = f2bf((acc[mi][ni][r] + bv) * scale);
                }
        }
        __syncthreads();
        int row = tid >> 1, h2 = tid & 1;           // 512 threads, 256 rows
        size_t gm = (size_t)(m0 + row);
        for (int i = 0; i < 8; i++) {
            uint4 v = *(const uint4*)&epi[row * 132 + h2 * 64 + i * 8];
            *(uint4*)&QKb[gm * 1536 + n0 + h2 * 64 + i * 8] = v;
        }
    } else {
        for (int ni = 0; ni < 4; ni++) {
            int nl = wn * 64 + ni * 16 + l15;
            float bv = bias[n0 + nl];
            for (int mi = 0; mi < 4; mi++) {
                int ml = wm * 64 + mi * 16 + quad * 4;
                ushort4 p4;
                p4.x = f2bf(acc[mi][ni][0] + bv);
                p4.y = f2bf(acc[mi][ni][1] + bv);
                p4.z = f2bf(acc[mi][ni][2] + bv);
                p4.w = f2bf(acc[mi][ni][3] + bv);
                *(ushort4*)&epi[nl * 264 + ml] = p4;
            }
        }
        __syncthreads();
        int row = tid >> 2, q4 = tid & 3;           // 128 rows x 4 col-quarters
        int nn = n0 + row - 1536;
        int hh = nn >> 6, d = nn & 63;
        int bb = m0 >> 11, s0 = m0 & 2047;          // 256 | 2048 so bb uniform
        for (int i = 0; i < 8; i++) {
            uint4 v = *(const uint4*)&epi[row * 264 + q4 * 64 + i * 8];
            *(uint4*)&Vt[((size_t)(bb * NH + hh) * HD + d) * S_LEN + s0 + q4 * 64 + i * 8] = v;
        }
    }
}

// ---------------- Attention: ReLU(Q K^T, causal) @ V  (Q pre-scaled) --------
// Paired q-tiles: each block processes q-tiles (2j, 2j+1) of one (b,h) against
// ONE shared K/V stream (staged in LDS, double-buffered, XOR-swizzled).
// Halves barrier count & K/V traffic per FLOP; ~128 MFMA per wave-stage hides
// the prefetch drain. V fragments hoisted per jsub, shared by both q-tiles.
// PV via 16x16x32 with permlane cross-quad repack. 384 blocks, heavy pairs
// (j=7, 16 stages) first.
__global__ __launch_bounds__(256, 2) void attn(const ushort* __restrict__ QKb,
                                               const ushort* __restrict__ Vt,
                                               float* __restrict__ out) {
    __shared__ ushort lds[32768];   // 64KB: K buffers @0/16384B; V @32768/49152B
    char* ldsb = (char*)lds;
    int tid = threadIdx.x;
    int w = tid >> 6, lane = tid & 63;
    int l15 = lane & 15, quad = lane >> 4;
    int r8 = lane >> 3, cc = lane & 7;

    // ---- hoisted lane-dependent offsets (loop-invariant) ----
    int kfo[2];
    for (int ch = 0; ch < 2; ch++)
        kfo[ch] = l15 * 128 + ((ch * 4 + quad) ^ (l15 & 7)) * 16;
    // V b128 fragment offsets: 32-k tile T (0..3): d-row l15 (+ni*4096), slot T*4+quad
    int vfo2[4];
    for (int T = 0; T < 4; T++)
        vfo2[T] = 32768 + l15 * 256 + ((T * 4 + quad) ^ l15) * 16;
    int rhs[2] = { w * 32 + l15, w * 32 + 16 + l15 };   // causal threshold (qt cancels)
    int kgo = (w * 32 + r8) * 3072 + (cc ^ r8) * 16;    // K staging (QKb row = 3072 B)
    int vgo[4];
    for (int i = 0; i < 4; i++)
        vgo[i] = (w * 16 + i * 4 + quad) * 4096 + ((l15 ^ ((i * 4 + quad) & 15)) * 16);
    int kst = (w * 32) * 128;            // LDS K dst, + i*1024 + p*16384
    int vst = 32768 + (w * 16) * 256;    // LDS V dst, + i*1024 + p*16384

    // ---- pair schedule: 384 blocks = 48 bh x 8 pairs; heavy pairs first ----
    int b = blockIdx.x;
    int j = 7 - b / 48, bh = b % 48;
    int qts2[2] = { 2 * j, 2 * j + 1 };
    int bg = bh / NH, h = bh % NH;
    const char* kg = (const char*)(QKb + (size_t)bg * S_LEN * 1536 + 768 + h * 64) + kgo;
    const char* vgb = (const char*)(Vt + (size_t)bh * HD * S_LEN);

    auto prefetch = [&](int st, int dstP) {
        const char* kbase = kg + (size_t)st * 393216;
        const char* vbase = vgb + st * 256;
        for (int i = 0; i < 4; i++)
            gl_lds16(kbase + i * 24576, ldsb + dstP * 16384 + kst + i * 1024);
        for (int i = 0; i < 4; i++)
            gl_lds16(vbase + vgo[i], ldsb + dstP * 16384 + vst + i * 1024);
    };

    // Q fragments for both tiles (loop-invariant)
    const ushort* Qcol = QKb + (size_t)bg * S_LEN * 1536 + h * 64;
    short8 qf[2][2][2];
    for (int tq = 0; tq < 2; tq++)
        for (int nq = 0; nq < 2; nq++)
            for (int ch = 0; ch < 2; ch++)
                qf[tq][nq][ch] = *(const short8*)(Qcol +
                    (size_t)(qts2[tq] * 128 + w * 32 + nq * 16 + l15) * 1536 + ch * 32 + quad * 8);

    floatx4 acco[2][2][4] = {};
    int nst = qts2[1] + 1;
    int p = 0;
    prefetch(0, 0);
    for (int st = 0; st < nst; st++) {
        __syncthreads();                       // sole barrier: buf[p] staged; buf[p^1] free
        if (st + 1 < nst) prefetch(st + 1, p ^ 1);

        const char* kb = ldsb + p * 16384;

#pragma unroll
        for (int jsub = 0; jsub < 2; jsub++) {
            // V fragments for this 64-k half, shared by both q-tiles
            short8 vf[2][4];
            for (int pr = 0; pr < 2; pr++) {
                int T = jsub * 2 + pr;
                for (int ni = 0; ni < 4; ni++)
                    vf[pr][ni] = *(const short8*)(kb + vfo2[T] + ni * 4096);
            }

#pragma unroll
            for (int tq = 0; tq < 2; tq++) {
                if (st > qts2[tq]) continue;       // tile A done at the last stage
                bool diag = (st == qts2[tq]);

                // S^T = K·Q^T : 64 k-rows x 32 q, K(d)=64
                floatx4 stc[4][2] = {};
                __builtin_amdgcn_s_setprio(1);
                for (int ch = 0; ch < 2; ch++) {
                    short8 kf[4];
                    for (int mk = 0; mk < 4; mk++)
                        kf[mk] = *(const short8*)(kb + kfo[ch] + jsub * 8192 + mk * 2048);
                    for (int mk = 0; mk < 4; mk++)
                        for (int nq = 0; nq < 2; nq++)
                            stc[mk][nq] = __builtin_amdgcn_mfma_f32_16x16x32_bf16(
                                kf[mk], qf[tq][nq][ch], stc[mk][nq], 0, 0, 0);
                }
                __builtin_amdgcn_s_setprio(0);

                // ReLU + causal mask + pack (k = quad*4 + r layout, 2 bf16/uint)
                unsigned int pk[4][2][2];
                for (int mk = 0; mk < 4; mk++) {
                    for (int nq = 0; nq < 2; nq++) {
                        float e[4];
                        for (int r = 0; r < 4; r++)
                            e[r] = fmaxf(stc[mk][nq][r], 0.0f);
                        if (diag) {
                            int kl = jsub * 64 + mk * 16 + quad * 4;
                            for (int r = 0; r < 4; r++)
                                if (kl + r > rhs[nq]) e[r] = 0.0f;
                        }
                        pk[mk][nq][0] = pack2bf(e[0], e[1]);
                        pk[mk][nq][1] = pack2bf(e[2], e[3]);
                    }
                }

                // O += P·V via 16x16x32: repack P cross-quad with permlane swaps
                __builtin_amdgcn_s_setprio(1);
                for (int pr = 0; pr < 2; pr++) {
                    for (int mi = 0; mi < 2; mi++) {
                        unsigned int a0 = pk[2 * pr][mi][0], a1 = pk[2 * pr][mi][1];
                        unsigned int b0 = pk[2 * pr + 1][mi][0], b1 = pk[2 * pr + 1][mi][1];
                        pl32_swap(a0, b0);  pl32_swap(a1, b1);
                        pl16_swap(a0, b0);  pl16_swap(a1, b1);
                        // now: a0=k q*8+{0,1}, a1=+{2,3}, b0=+{4,5}, b1=+{6,7}
                        short8 af = __builtin_bit_cast(short8, (uint4v){a0, a1, b0, b1});
                        for (int ni = 0; ni < 4; ni++)
                            acco[tq][mi][ni] = __builtin_amdgcn_mfma_f32_16x16x32_bf16(
                                af, vf[pr][ni], acco[tq][mi][ni], 0, 0, 0);
                    }
                }
                __builtin_amdgcn_s_setprio(0);
            }
        }
        p ^= 1;
    }

    // epilogue: out[b][s][h*64+d] fp32, both q-tiles
    for (int tq = 0; tq < 2; tq++) {
        for (int mi = 0; mi < 2; mi++) {
            for (int ni = 0; ni < 4; ni++) {
                int d = ni * 16 + l15;
                for (int r = 0; r < 4; r++) {
                    int s = qts2[tq] * 128 + w * 32 + mi * 16 + quad * 4 + r;
                    out[((size_t)bg * S_LEN + s) * EMB + h * 64 + d] = acco[tq][mi][ni][r];
                }
            }
        }
    }
}

extern "C" void kernel_launch(void* const* d_in, const int* in_sizes, int n_in,
                              void* d_out, int out_size, void* d_ws, size_t ws_size,
                              hipStream_t stream) {
    const float* x    = (const float*)d_in[0];   // [4,2048,768]
    const float* W    = (const float*)d_in[1];   // [768,2304]
    const float* bias = (const float*)d_in[2];   // [2304]
    float* out = (float*)d_out;                  // [4,2048,768] fp32

    char* ws = (char*)d_ws;
    const size_t SZ_X  = (size_t)8192 * EMB * 2;
    const size_t SZ_W  = (size_t)E3 * EMB * 2;
    const size_t SZ_QK = (size_t)8192 * 1536 * 2;
    ushort* Xb  = (ushort*)(ws);
    ushort* Wt  = (ushort*)(ws + SZ_X);
    ushort* QKb = (ushort*)(ws + SZ_X + SZ_W);
    ushort* Vt  = (ushort*)(ws + SZ_X + SZ_W + SZ_QK);

    static bool attr_done = false;
    if (!attr_done) {
        hipFuncSetAttribute((const void*)qkv_gemm,
                            hipFuncAttributeMaxDynamicSharedMemorySize, 147456);
        attr_done = true;
    }

    conv_fused<<<dim3(6144 + 1728), dim3(256), 0, stream>>>(x, Xb, W, Wt);
    qkv_gemm<<<dim3(32, 18), dim3(512), 147456, stream>>>(Xb, Wt, bias, QKb, Vt);
    attn<<<dim3(384), dim3(256), 0, stream>>>(QKb, Vt, out);
}

// Round 7
// 186.002 us; speedup vs baseline: 1.0581x; 1.0205x over previous
//
#include <hip/hip_runtime.h>

typedef __attribute__((ext_vector_type(8))) short short8;
typedef __attribute__((ext_vector_type(4))) float floatx4;
typedef __attribute__((ext_vector_type(4))) unsigned int uint4v;

#define S_LEN 2048
#define NH 12
#define HD 64
#define EMB 768
#define E3 2304

#define MF(a, b, c) __builtin_amdgcn_mfma_f32_16x16x32_bf16(a, b, c, 0, 0, 0)

__device__ __forceinline__ unsigned short f2bf(float f) {
    unsigned int u = __builtin_bit_cast(unsigned int, f);
    u += 0x7FFFu + ((u >> 16) & 1u);   // RNE
    return (unsigned short)(u >> 16);
}

__device__ __forceinline__ unsigned int pack2bf(float a, float b) {
#if __has_builtin(__builtin_amdgcn_cvt_pk_bf16_f32)
    typedef __attribute__((ext_vector_type(2))) short short2v;
    short2v r = __builtin_amdgcn_cvt_pk_bf16_f32(a, b);
    return __builtin_bit_cast(unsigned int, r);
#else
    return (unsigned int)f2bf(a) | ((unsigned int)f2bf(b) << 16);
#endif
}

// gfx950 cross-quad swaps: vdst[hi]<->vsrc[lo] at 32/16-lane granularity
__device__ __forceinline__ void pl32_swap(unsigned int& x, unsigned int& y) {
#if __has_builtin(__builtin_amdgcn_permlane32_swap)
    typedef __attribute__((ext_vector_type(2))) unsigned int uint2v_;
    uint2v_ r = __builtin_amdgcn_permlane32_swap(x, y, false, false);
    x = r[0]; y = r[1];
#else
    asm("v_permlane32_swap_b32 %0, %1" : "+v"(x), "+v"(y));
#endif
}
__device__ __forceinline__ void pl16_swap(unsigned int& x, unsigned int& y) {
#if __has_builtin(__builtin_amdgcn_permlane16_swap)
    typedef __attribute__((ext_vector_type(2))) unsigned int uint2v_;
    uint2v_ r = __builtin_amdgcn_permlane16_swap(x, y, false, false);
    x = r[0]; y = r[1];
#else
    asm("v_permlane16_swap_b32 %0, %1" : "+v"(x), "+v"(y));
#endif
}

// async global->LDS, 16B/lane; LDS dest = wave-uniform base + lane*16
__device__ __forceinline__ void gl_lds16(const void* g, void* l) {
    __builtin_amdgcn_global_load_lds(
        (const __attribute__((address_space(1))) unsigned int*)g,
        (__attribute__((address_space(3))) unsigned int*)l, 16, 0, 0);
}

// ------------- fused input conversion: x->bf16, W->Wt bf16 -------------------
__global__ __launch_bounds__(256) void conv_fused(const float* __restrict__ x,
                                                  ushort* __restrict__ xb,
                                                  const float* __restrict__ W,
                                                  ushort* __restrict__ Wt) {
    int tid = threadIdx.x;
    if (blockIdx.x < 6144) {                      // x: 8192*768 / 4 per thread
        int i = (blockIdx.x * 256 + tid) * 4;
        float4 f = *(const float4*)(x + i);
        ushort4 o;
        o.x = f2bf(f.x); o.y = f2bf(f.y); o.z = f2bf(f.z); o.w = f2bf(f.w);
        *(ushort4*)(xb + i) = o;
    } else {                                      // W transpose: 72 x 24 tiles of 32x32
        __shared__ float tile[32][33];
        int b2 = blockIdx.x - 6144;
        int n0 = (b2 % 72) * 32, k0 = (b2 / 72) * 32;
        int tx = tid & 31, ty = tid >> 5;
        for (int i = 0; i < 4; i++)
            tile[ty + i * 8][tx] = W[(size_t)(k0 + ty + i * 8) * E3 + n0 + tx];
        __syncthreads();
        for (int i = 0; i < 4; i++)
            Wt[(size_t)(n0 + ty + i * 8) * EMB + k0 + tx] = f2bf(tile[tx][ty + i * 8]);
    }
}

// ---------------- QKV GEMM: [8192,768] x [768,2304] + bias ----------------
// 256x128 tile, 8 waves (4M x 2N), BK=64 (12 K-tiles), 3-deep LDS ring buffer
// (48 KB/tile, 144 KB total, WAR-free: stage t+2 overwrites t-1), 4 phases per
// K-tile with counted vmcnt(6) (never 0 in loop), raw s_barrier, setprio(1)
// around MFMA clusters. XOR-swizzled gl_lds staging (slot cc^row&7).
__global__ __launch_bounds__(512, 1) void qkv_gemm(const ushort* __restrict__ Xb,
                                                   const ushort* __restrict__ Wt,
                                                   const float* __restrict__ bias,
                                                   ushort* __restrict__ QKb,
                                                   ushort* __restrict__ Vt) {
    extern __shared__ char ldsb[];                 // 147456 B dynamic
    const int tid  = threadIdx.x;
    const int w = tid >> 6, lane = tid & 63;
    const int l15 = lane & 15, quad = lane >> 4;
    const int r8 = lane >> 3, cc = lane & 7;
    const int wm = w >> 1, wn = w & 1;             // 4M x 2N wave grid
    const int m0 = blockIdx.x * 256, n0 = blockIdx.y * 128;

    floatx4 acc[4][4] = {};

    // staging sources (bytes); X/Wt row stride = 1536 B; +t*128 per K-tile
    const char* agp = (const char*)Xb + (size_t)(m0 + w * 32 + r8) * 1536 + (cc ^ r8) * 16;
    const char* bgp = (const char*)Wt + (size_t)(n0 + w * 16 + r8) * 1536 + (cc ^ r8) * 16;
    const int adstB = w * 4096;                    // + i*1024 (i<4), A region 32 KB
    const int bdstB = 32768 + w * 2048;            // + i*1024 (i<2), B region 16 KB

    // fragment read addressing (swizzle slot = (kk*4+quad) ^ (row&7))
    const int aroB = (wm * 64 + l15) * 128;        // + mi*2048 + swz[kk]
    const int broB = 32768 + (wn * 64 + l15) * 128;// + ni*2048 + swz[kk]
    const int swz0 = ((quad) ^ (l15 & 7)) * 16;
    const int swz1 = ((4 + quad) ^ (l15 & 7)) * 16;

    // prologue: stage K-tiles 0 and 1 (6 gl_lds insts each)
    for (int i = 0; i < 4; i++) gl_lds16(agp + i * 12288, ldsb + adstB + i * 1024);
    for (int i = 0; i < 2; i++) gl_lds16(bgp + i * 12288, ldsb + bdstB + i * 1024);
    for (int i = 0; i < 4; i++) gl_lds16(agp + 128 + i * 12288, ldsb + 49152 + adstB + i * 1024);
    for (int i = 0; i < 2; i++) gl_lds16(bgp + 128 + i * 12288, ldsb + 49152 + bdstB + i * 1024);

#pragma unroll
    for (int t = 0; t < 12; ++t) {
        // iteration-start wait: K-tile t landed (newest 6 insts = K-tile t+1 may fly)
        if (t < 11) asm volatile("s_waitcnt vmcnt(6)" ::: "memory");
        else        asm volatile("s_waitcnt vmcnt(0)" ::: "memory");
        __builtin_amdgcn_s_barrier();
        __builtin_amdgcn_sched_barrier(0);         // no read hoists above this point

        const char* base = ldsb + (t % 3) * 49152;
        char* sdst = ldsb + ((t + 2) % 3) * 49152; // holds K-tile t-1: reads done
        const int koff = (t + 2) * 128;
        const bool st = (t < 10);

        short8 af0, af1, bf0, bf1, bf2, bf3;

        // ---- phase 0: kk=0, m-half 0 (loads B kk=0) | stage A units 0,1 ----
        af0 = *(const short8*)(base + aroB + 0 * 2048 + swz0);
        af1 = *(const short8*)(base + aroB + 1 * 2048 + swz0);
        bf0 = *(const short8*)(base + broB + 0 * 2048 + swz0);
        bf1 = *(const short8*)(base + broB + 1 * 2048 + swz0);
        bf2 = *(const short8*)(base + broB + 2 * 2048 + swz0);
        bf3 = *(const short8*)(base + broB + 3 * 2048 + swz0);
        if (st) { gl_lds16(agp + koff,         sdst + adstB);
                  gl_lds16(agp + koff + 12288, sdst + adstB + 1024); }
        __builtin_amdgcn_s_setprio(1);
        acc[0][0] = MF(af0, bf0, acc[0][0]); acc[0][1] = MF(af0, bf1, acc[0][1]);
        acc[0][2] = MF(af0, bf2, acc[0][2]); acc[0][3] = MF(af0, bf3, acc[0][3]);
        acc[1][0] = MF(af1, bf0, acc[1][0]); acc[1][1] = MF(af1, bf1, acc[1][1]);
        acc[1][2] = MF(af1, bf2, acc[1][2]); acc[1][3] = MF(af1, bf3, acc[1][3]);
        __builtin_amdgcn_s_setprio(0);
        __builtin_amdgcn_s_barrier();

        // ---- phase 1: kk=0, m-half 1 (reuses B kk=0) | stage A units 2,3 ----
        af0 = *(const short8*)(base + aroB + 2 * 2048 + swz0);
        af1 = *(const short8*)(base + aroB + 3 * 2048 + swz0);
        if (st) { gl_lds16(agp + koff + 2 * 12288, sdst + adstB + 2048);
                  gl_lds16(agp + koff + 3 * 12288, sdst + adstB + 3072); }
        __builtin_amdgcn_s_setprio(1);
        acc[2][0] = MF(af0, bf0, acc[2][0]); acc[2][1] = MF(af0, bf1, acc[2][1]);
        acc[2][2] = MF(af0, bf2, acc[2][2]); acc[2][3] = MF(af0, bf3, acc[2][3]);
        acc[3][0] = MF(af1, bf0, acc[3][0]); acc[3][1] = MF(af1, bf1, acc[3][1]);
        acc[3][2] = MF(af1, bf2, acc[3][2]); acc[3][3] = MF(af1, bf3, acc[3][3]);
        __builtin_amdgcn_s_setprio(0);
        __builtin_amdgcn_s_barrier();

        // ---- phase 2: kk=1, m-half 0 (loads B kk=1) | stage B units 0,1 ----
        af0 = *(const short8*)(base + aroB + 0 * 2048 + swz1);
        af1 = *(const short8*)(base + aroB + 1 * 2048 + swz1);
        bf0 = *(const short8*)(base + broB + 0 * 2048 + swz1);
        bf1 = *(const short8*)(base + broB + 1 * 2048 + swz1);
        bf2 = *(const short8*)(base + broB + 2 * 2048 + swz1);
        bf3 = *(const short8*)(base + broB + 3 * 2048 + swz1);
        if (st) { gl_lds16(bgp + koff,         sdst + bdstB);
                  gl_lds16(bgp + koff + 12288, sdst + bdstB + 1024); }
        __builtin_amdgcn_s_setprio(1);
        acc[0][0] = MF(af0, bf0, acc[0][0]); acc[0][1] = MF(af0, bf1, acc[0][1]);
        acc[0][2] = MF(af0, bf2, acc[0][2]); acc[0][3] = MF(af0, bf3, acc[0][3]);
        acc[1][0] = MF(af1, bf0, acc[1][0]); acc[1][1] = MF(af1, bf1, acc[1][1]);
        acc[1][2] = MF(af1, bf2, acc[1][2]); acc[1][3] = MF(af1, bf3, acc[1][3]);
        __builtin_amdgcn_s_setprio(0);
        __builtin_amdgcn_s_barrier();

        // ---- phase 3: kk=1, m-half 1 (reuses B kk=1) | no stage ----
        af0 = *(const short8*)(base + aroB + 2 * 2048 + swz1);
        af1 = *(const short8*)(base + aroB + 3 * 2048 + swz1);
        __builtin_amdgcn_s_setprio(1);
        acc[2][0] = MF(af0, bf0, acc[2][0]); acc[2][1] = MF(af0, bf1, acc[2][1]);
        acc[2][2] = MF(af0, bf2, acc[2][2]); acc[2][3] = MF(af0, bf3, acc[2][3]);
        acc[3][0] = MF(af1, bf0, acc[3][0]); acc[3][1] = MF(af1, bf1, acc[3][1]);
        acc[3][2] = MF(af1, bf2, acc[3][2]); acc[3][3] = MF(af1, bf3, acc[3][3]);
        __builtin_amdgcn_s_setprio(0);
        // next iteration's start barrier closes this K-tile
    }

    // ---------------- epilogue (LDS reused after full drain) ----------------
    __syncthreads();
    ushort* epi = (ushort*)ldsb;
    int seg = n0 >= 1536 ? 2 : (n0 >= 768 ? 1 : 0);
    if (seg < 2) {
        float scale = (seg == 0) ? 0.125f : 1.0f;   // fold attention scale into Q
        for (int ni = 0; ni < 4; ni++) {
            int nl = wn * 64 + ni * 16 + l15;
            float bv = bias[n0 + nl];
            for (int mi = 0; mi < 4; mi++)
                for (int r = 0; r < 4; r++) {
                    int ml = wm * 64 + mi * 16 + quad * 4 + r;
                    epi[ml * 132 + nl] = f2bf((acc[mi][ni][r] + bv) * scale);
                }
        }
        __syncthreads();
        int row = tid >> 1, h2 = tid & 1;           // 512 threads, 256 rows
        size_t gm = (size_t)(m0 + row);
        for (int i = 0; i < 8; i++) {
            uint4 v = *(const uint4*)&epi[row * 132 + h2 * 64 + i * 8];
            *(uint4*)&QKb[gm * 1536 + n0 + h2 * 64 + i * 8] = v;
        }
    } else {
        for (int ni = 0; ni < 4; ni++) {
            int nl = wn * 64 + ni * 16 + l15;
            float bv = bias[n0 + nl];
            for (int mi = 0; mi < 4; mi++) {
                int ml = wm * 64 + mi * 16 + quad * 4;
                ushort4 p4;
                p4.x = f2bf(acc[mi][ni][0] + bv);
                p4.y = f2bf(acc[mi][ni][1] + bv);
                p4.z = f2bf(acc[mi][ni][2] + bv);
                p4.w = f2bf(acc[mi][ni][3] + bv);
                *(ushort4*)&epi[nl * 264 + ml] = p4;
            }
        }
        __syncthreads();
        int row = tid >> 2, q4 = tid & 3;           // 128 rows x 4 col-quarters
        int nn = n0 + row - 1536;
        int hh = nn >> 6, d = nn & 63;
        int bb = m0 >> 11, s0 = m0 & 2047;          // 256 | 2048 so bb uniform
        for (int i = 0; i < 8; i++) {
            uint4 v = *(const uint4*)&epi[row * 264 + q4 * 64 + i * 8];
            *(uint4*)&Vt[((size_t)(bb * NH + hh) * HD + d) * S_LEN + s0 + q4 * 64 + i * 8] = v;
        }
    }
}

// ---------------- Attention: ReLU(Q K^T, causal) @ V  (Q pre-scaled) --------
// Fine-grained variant of the proven round-2 dataflow: 128-thread blocks
// (2 waves), 64-row q-tiles, 64-col K/V stages, double-buffered XOR-swizzled
// LDS staging (32 KB/block -> 5 blocks/CU, 10 waves/CU), 1536 blocks
// heavy-first. PV via 16x16x32 + permlane cross-quad repack. Plain stores.
__global__ __launch_bounds__(128, 2) void attn(const ushort* __restrict__ QKb,
                                               const ushort* __restrict__ Vt,
                                               float* __restrict__ out) {
    __shared__ ushort lds[16384];   // 32KB: K @0/8192; V @16384/24576
    char* ldsb = (char*)lds;
    int tid = threadIdx.x;
    int w = tid >> 6, lane = tid & 63;              // w in {0,1}
    int l15 = lane & 15, quad = lane >> 4;
    int r8 = lane >> 3, cc = lane & 7;

    // ---- hoisted lane-dependent offsets (loop-invariant) ----
    // K LDS: [64 k-rows][64 d], row = 128 B, 8 slots of 16 B, swz slot^ (row&7)
    int kfo[2];
    for (int ch = 0; ch < 2; ch++)
        kfo[ch] = l15 * 128 + ((ch * 4 + quad) ^ (l15 & 7)) * 16;
    // V LDS: [64 d-rows][64 k], row = 128 B; read row ni*16+l15, slot T*4+quad
    int vfo[2];
    for (int T = 0; T < 2; T++)
        vfo[T] = 16384 + l15 * 128 + ((T * 4 + quad) ^ (l15 & 7)) * 16;
    int rhs[2] = { w * 32 + l15, w * 32 + 16 + l15 };   // causal threshold in-stage
    int kgo = (w * 32 + r8) * 3072 + (cc ^ r8) * 16;    // K staging (QKb row = 3072 B)
    int vgo[4];
    for (int i = 0; i < 4; i++)                         // V row w*32+i*8+r8, swz cc^r8
        vgo[i] = (w * 32 + i * 8 + r8) * 4096 + (cc ^ r8) * 16;
    int kst = (w * 32) * 128;            // LDS K dst + i*1024 + p*8192
    int vst = 16384 + (w * 32) * 128;    // LDS V dst + i*1024 + p*8192

    // ---- schedule: 1536 blocks = 32 q-subtiles x 48 bh, heavy-first ----
    int b = blockIdx.x;
    int qs = 31 - b / 48, bh = b % 48;   // q rows [qs*64, qs*64+64)
    int bg = bh / NH, h = bh % NH;

    const char* kg = (const char*)(QKb + (size_t)bg * S_LEN * 1536 + 768 + h * 64) + kgo;
    const char* vgb = (const char*)(Vt + (size_t)bh * HD * S_LEN);

    auto prefetch = [&](int st, int dstP) {
        const char* kbase = kg + (size_t)st * 196608;   // 64 k-rows x 3072 B
        const char* vbase = vgb + st * 128;             // 64 k-cols x 2 B
        for (int i = 0; i < 4; i++)
            gl_lds16(kbase + i * 24576, ldsb + dstP * 8192 + kst + i * 1024);
        for (int i = 0; i < 4; i++)
            gl_lds16(vbase + vgo[i], ldsb + dstP * 8192 + vst + i * 1024);
    };

    // Q fragments (loop-invariant)
    const ushort* Qcol = QKb + (size_t)bg * S_LEN * 1536 + h * 64;
    short8 qf[2][2];
    for (int nq = 0; nq < 2; nq++)
        for (int ch = 0; ch < 2; ch++)
            qf[nq][ch] = *(const short8*)(Qcol +
                (size_t)(qs * 64 + w * 32 + nq * 16 + l15) * 1536 + ch * 32 + quad * 8);

    floatx4 acco[2][4] = {};
    int p = 0;
    prefetch(0, 0);
    int nst = qs + 1;                    // 64-col stages to cover k <= q
    for (int st = 0; st < nst; st++) {
        __syncthreads();                 // sole barrier: buf[p] staged; buf[p^1] free
        if (st + 1 < nst) prefetch(st + 1, p ^ 1);

        bool diag = (st == qs);
        const char* kb = ldsb + p * 8192;

        // S^T = K·Q^T : 64 k-rows x 32 q, K(d)=64
        floatx4 stc[4][2] = {};
        for (int ch = 0; ch < 2; ch++) {
            short8 kf[4];
            for (int mk = 0; mk < 4; mk++)
                kf[mk] = *(const short8*)(kb + kfo[ch] + mk * 2048);
            for (int mk = 0; mk < 4; mk++)
                for (int nq = 0; nq < 2; nq++)
                    stc[mk][nq] = __builtin_amdgcn_mfma_f32_16x16x32_bf16(
                        kf[mk], qf[nq][ch], stc[mk][nq], 0, 0, 0);
        }

        // ReLU + causal mask + pack (k = quad*4 + r layout, 2 bf16/uint)
        unsigned int pk[4][2][2];
        for (int mk = 0; mk < 4; mk++) {
            for (int nq = 0; nq < 2; nq++) {
                float e[4];
                for (int r = 0; r < 4; r++)
                    e[r] = fmaxf(stc[mk][nq][r], 0.0f);
                if (diag) {
                    int kl = mk * 16 + quad * 4;
                    for (int r = 0; r < 4; r++)
                        if (kl + r > rhs[nq]) e[r] = 0.0f;
                }
                pk[mk][nq][0] = pack2bf(e[0], e[1]);
                pk[mk][nq][1] = pack2bf(e[2], e[3]);
            }
        }

        // O += P·V via 16x16x32: repack P cross-quad with permlane swaps
        for (int pr = 0; pr < 2; pr++) {
            short8 vf[4];
            for (int ni = 0; ni < 4; ni++)
                vf[ni] = *(const short8*)(kb + vfo[pr] + ni * 2048);
            for (int mi = 0; mi < 2; mi++) {
                unsigned int a0 = pk[2 * pr][mi][0], a1 = pk[2 * pr][mi][1];
                unsigned int b0 = pk[2 * pr + 1][mi][0], b1 = pk[2 * pr + 1][mi][1];
                pl32_swap(a0, b0);  pl32_swap(a1, b1);
                pl16_swap(a0, b0);  pl16_swap(a1, b1);
                // now: a0=k q*8+{0,1}, a1=+{2,3}, b0=+{4,5}, b1=+{6,7}
                short8 af = __builtin_bit_cast(short8, (uint4v){a0, a1, b0, b1});
                for (int ni = 0; ni < 4; ni++)
                    acco[mi][ni] = __builtin_amdgcn_mfma_f32_16x16x32_bf16(
                        af, vf[ni], acco[mi][ni], 0, 0, 0);
            }
        }
        p ^= 1;
    }

    // epilogue: out[b][s][h*64+d] fp32, plain stores (each row written once)
    for (int mi = 0; mi < 2; mi++) {
        for (int ni = 0; ni < 4; ni++) {
            int d = ni * 16 + l15;
            for (int r = 0; r < 4; r++) {
                int s = qs * 64 + w * 32 + mi * 16 + quad * 4 + r;
                out[((size_t)bg * S_LEN + s) * EMB + h * 64 + d] = acco[mi][ni][r];
            }
        }
    }
}

extern "C" void kernel_launch(void* const* d_in, const int* in_sizes, int n_in,
                              void* d_out, int out_size, void* d_ws, size_t ws_size,
                              hipStream_t stream) {
    const float* x    = (const float*)d_in[0];   // [4,2048,768]
    const float* W    = (const float*)d_in[1];   // [768,2304]
    const float* bias = (const float*)d_in[2];   // [2304]
    float* out = (float*)d_out;                  // [4,2048,768] fp32

    char* ws = (char*)d_ws;
    const size_t SZ_X  = (size_t)8192 * EMB * 2;
    const size_t SZ_W  = (size_t)E3 * EMB * 2;
    const size_t SZ_QK = (size_t)8192 * 1536 * 2;
    ushort* Xb  = (ushort*)(ws);
    ushort* Wt  = (ushort*)(ws + SZ_X);
    ushort* QKb = (ushort*)(ws + SZ_X + SZ_W);
    ushort* Vt  = (ushort*)(ws + SZ_X + SZ_W + SZ_QK);

    static bool attr_done = false;
    if (!attr_done) {
        hipFuncSetAttribute((const void*)qkv_gemm,
                            hipFuncAttributeMaxDynamicSharedMemorySize, 147456);
        attr_done = true;
    }

    conv_fused<<<dim3(6144 + 1728), dim3(256), 0, stream>>>(x, Xb, W, Wt);
    qkv_gemm<<<dim3(32, 18), dim3(512), 147456, stream>>>(Xb, Wt, bias, QKb, Vt);
    attn<<<dim3(1536), dim3(128), 0, stream>>>(QKb, Vt, out);
}

// Round 8
// 177.312 us; speedup vs baseline: 1.1100x; 1.0490x over previous
//
#include <hip/hip_runtime.h>

typedef __attribute__((ext_vector_type(8))) short short8;
typedef __attribute__((ext_vector_type(4))) float floatx4;
typedef __attribute__((ext_vector_type(4))) unsigned int uint4v;

#define S_LEN 2048
#define NH 12
#define HD 64
#define EMB 768
#define E3 2304

#define MF(a, b, c) __builtin_amdgcn_mfma_f32_16x16x32_bf16(a, b, c, 0, 0, 0)

__device__ __forceinline__ unsigned short f2bf(float f) {
    unsigned int u = __builtin_bit_cast(unsigned int, f);
    u += 0x7FFFu + ((u >> 16) & 1u);   // RNE
    return (unsigned short)(u >> 16);
}

__device__ __forceinline__ unsigned int pack2bf(float a, float b) {
#if __has_builtin(__builtin_amdgcn_cvt_pk_bf16_f32)
    typedef __attribute__((ext_vector_type(2))) short short2v;
    short2v r = __builtin_amdgcn_cvt_pk_bf16_f32(a, b);
    return __builtin_bit_cast(unsigned int, r);
#else
    return (unsigned int)f2bf(a) | ((unsigned int)f2bf(b) << 16);
#endif
}

// gfx950 cross-quad swaps: vdst[hi]<->vsrc[lo] at 32/16-lane granularity
__device__ __forceinline__ void pl32_swap(unsigned int& x, unsigned int& y) {
#if __has_builtin(__builtin_amdgcn_permlane32_swap)
    typedef __attribute__((ext_vector_type(2))) unsigned int uint2v_;
    uint2v_ r = __builtin_amdgcn_permlane32_swap(x, y, false, false);
    x = r[0]; y = r[1];
#else
    asm("v_permlane32_swap_b32 %0, %1" : "+v"(x), "+v"(y));
#endif
}
__device__ __forceinline__ void pl16_swap(unsigned int& x, unsigned int& y) {
#if __has_builtin(__builtin_amdgcn_permlane16_swap)
    typedef __attribute__((ext_vector_type(2))) unsigned int uint2v_;
    uint2v_ r = __builtin_amdgcn_permlane16_swap(x, y, false, false);
    x = r[0]; y = r[1];
#else
    asm("v_permlane16_swap_b32 %0, %1" : "+v"(x), "+v"(y));
#endif
}

// async global->LDS, 16B/lane; LDS dest = wave-uniform base + lane*16
__device__ __forceinline__ void gl_lds16(const void* g, void* l) {
    __builtin_amdgcn_global_load_lds(
        (const __attribute__((address_space(1))) unsigned int*)g,
        (__attribute__((address_space(3))) unsigned int*)l, 16, 0, 0);
}

// ------------- fused input conversion: x->bf16, W->Wt bf16 -------------------
__global__ __launch_bounds__(256) void conv_fused(const float* __restrict__ x,
                                                  ushort* __restrict__ xb,
                                                  const float* __restrict__ W,
                                                  ushort* __restrict__ Wt) {
    int tid = threadIdx.x;
    if (blockIdx.x < 6144) {                      // x: 8192*768 / 4 per thread
        int i = (blockIdx.x * 256 + tid) * 4;
        float4 f = *(const float4*)(x + i);
        ushort4 o;
        o.x = f2bf(f.x); o.y = f2bf(f.y); o.z = f2bf(f.z); o.w = f2bf(f.w);
        *(ushort4*)(xb + i) = o;
    } else {                                      // W transpose: 72 x 24 tiles of 32x32
        __shared__ float tile[32][33];
        int b2 = blockIdx.x - 6144;
        int n0 = (b2 % 72) * 32, k0 = (b2 / 72) * 32;
        int tx = tid & 31, ty = tid >> 5;
        for (int i = 0; i < 4; i++)
            tile[ty + i * 8][tx] = W[(size_t)(k0 + ty + i * 8) * E3 + n0 + tx];
        __syncthreads();
        for (int i = 0; i < 4; i++)
            Wt[(size_t)(n0 + ty + i * 8) * EMB + k0 + tx] = f2bf(tile[tx][ty + i * 8]);
    }
}

// ---------------- QKV GEMM: [8192,768] x [768,2304] + bias ----------------
// 256x128 tile, 8 waves (4M x 2N), BK=64 (12 K-tiles), 3-deep LDS ring buffer
// (48 KB/tile, 144 KB total, WAR-free: stage t+2 overwrites t-1), 4 phases per
// K-tile with counted vmcnt(6) (never 0 in loop), raw s_barrier, setprio(1)
// around MFMA clusters. XOR-swizzled gl_lds staging (slot cc^row&7).
__global__ __launch_bounds__(512, 1) void qkv_gemm(const ushort* __restrict__ Xb,
                                                   const ushort* __restrict__ Wt,
                                                   const float* __restrict__ bias,
                                                   ushort* __restrict__ QKb,
                                                   ushort* __restrict__ Vt) {
    extern __shared__ char ldsb[];                 // 147456 B dynamic
    const int tid  = threadIdx.x;
    const int w = tid >> 6, lane = tid & 63;
    const int l15 = lane & 15, quad = lane >> 4;
    const int r8 = lane >> 3, cc = lane & 7;
    const int wm = w >> 1, wn = w & 1;             // 4M x 2N wave grid
    const int m0 = blockIdx.x * 256, n0 = blockIdx.y * 128;

    floatx4 acc[4][4] = {};

    // staging sources (bytes); X/Wt row stride = 1536 B; +t*128 per K-tile
    const char* agp = (const char*)Xb + (size_t)(m0 + w * 32 + r8) * 1536 + (cc ^ r8) * 16;
    const char* bgp = (const char*)Wt + (size_t)(n0 + w * 16 + r8) * 1536 + (cc ^ r8) * 16;
    const int adstB = w * 4096;                    // + i*1024 (i<4), A region 32 KB
    const int bdstB = 32768 + w * 2048;            // + i*1024 (i<2), B region 16 KB

    // fragment read addressing (swizzle slot = (kk*4+quad) ^ (row&7))
    const int aroB = (wm * 64 + l15) * 128;        // + mi*2048 + swz[kk]
    const int broB = 32768 + (wn * 64 + l15) * 128;// + ni*2048 + swz[kk]
    const int swz0 = ((quad) ^ (l15 & 7)) * 16;
    const int swz1 = ((4 + quad) ^ (l15 & 7)) * 16;

    // prologue: stage K-tiles 0 and 1 (6 gl_lds insts each)
    for (int i = 0; i < 4; i++) gl_lds16(agp + i * 12288, ldsb + adstB + i * 1024);
    for (int i = 0; i < 2; i++) gl_lds16(bgp + i * 12288, ldsb + bdstB + i * 1024);
    for (int i = 0; i < 4; i++) gl_lds16(agp + 128 + i * 12288, ldsb + 49152 + adstB + i * 1024);
    for (int i = 0; i < 2; i++) gl_lds16(bgp + 128 + i * 12288, ldsb + 49152 + bdstB + i * 1024);

#pragma unroll
    for (int t = 0; t < 12; ++t) {
        // iteration-start wait: K-tile t landed (newest 6 insts = K-tile t+1 may fly)
        if (t < 11) asm volatile("s_waitcnt vmcnt(6)" ::: "memory");
        else        asm volatile("s_waitcnt vmcnt(0)" ::: "memory");
        __builtin_amdgcn_s_barrier();
        __builtin_amdgcn_sched_barrier(0);         // no read hoists above this point

        const char* base = ldsb + (t % 3) * 49152;
        char* sdst = ldsb + ((t + 2) % 3) * 49152; // holds K-tile t-1: reads done
        const int koff = (t + 2) * 128;
        const bool st = (t < 10);

        short8 af0, af1, bf0, bf1, bf2, bf3;

        // ---- phase 0: kk=0, m-half 0 (loads B kk=0) | stage A units 0,1 ----
        af0 = *(const short8*)(base + aroB + 0 * 2048 + swz0);
        af1 = *(const short8*)(base + aroB + 1 * 2048 + swz0);
        bf0 = *(const short8*)(base + broB + 0 * 2048 + swz0);
        bf1 = *(const short8*)(base + broB + 1 * 2048 + swz0);
        bf2 = *(const short8*)(base + broB + 2 * 2048 + swz0);
        bf3 = *(const short8*)(base + broB + 3 * 2048 + swz0);
        if (st) { gl_lds16(agp + koff,         sdst + adstB);
                  gl_lds16(agp + koff + 12288, sdst + adstB + 1024); }
        __builtin_amdgcn_s_setprio(1);
        acc[0][0] = MF(af0, bf0, acc[0][0]); acc[0][1] = MF(af0, bf1, acc[0][1]);
        acc[0][2] = MF(af0, bf2, acc[0][2]); acc[0][3] = MF(af0, bf3, acc[0][3]);
        acc[1][0] = MF(af1, bf0, acc[1][0]); acc[1][1] = MF(af1, bf1, acc[1][1]);
        acc[1][2] = MF(af1, bf2, acc[1][2]); acc[1][3] = MF(af1, bf3, acc[1][3]);
        __builtin_amdgcn_s_setprio(0);
        __builtin_amdgcn_s_barrier();

        // ---- phase 1: kk=0, m-half 1 (reuses B kk=0) | stage A units 2,3 ----
        af0 = *(const short8*)(base + aroB + 2 * 2048 + swz0);
        af1 = *(const short8*)(base + aroB + 3 * 2048 + swz0);
        if (st) { gl_lds16(agp + koff + 2 * 12288, sdst + adstB + 2048);
                  gl_lds16(agp + koff + 3 * 12288, sdst + adstB + 3072); }
        __builtin_amdgcn_s_setprio(1);
        acc[2][0] = MF(af0, bf0, acc[2][0]); acc[2][1] = MF(af0, bf1, acc[2][1]);
        acc[2][2] = MF(af0, bf2, acc[2][2]); acc[2][3] = MF(af0, bf3, acc[2][3]);
        acc[3][0] = MF(af1, bf0, acc[3][0]); acc[3][1] = MF(af1, bf1, acc[3][1]);
        acc[3][2] = MF(af1, bf2, acc[3][2]); acc[3][3] = MF(af1, bf3, acc[3][3]);
        __builtin_amdgcn_s_setprio(0);
        __builtin_amdgcn_s_barrier();

        // ---- phase 2: kk=1, m-half 0 (loads B kk=1) | stage B units 0,1 ----
        af0 = *(const short8*)(base + aroB + 0 * 2048 + swz1);
        af1 = *(const short8*)(base + aroB + 1 * 2048 + swz1);
        bf0 = *(const short8*)(base + broB + 0 * 2048 + swz1);
        bf1 = *(const short8*)(base + broB + 1 * 2048 + swz1);
        bf2 = *(const short8*)(base + broB + 2 * 2048 + swz1);
        bf3 = *(const short8*)(base + broB + 3 * 2048 + swz1);
        if (st) { gl_lds16(bgp + koff,         sdst + bdstB);
                  gl_lds16(bgp + koff + 12288, sdst + bdstB + 1024); }
        __builtin_amdgcn_s_setprio(1);
        acc[0][0] = MF(af0, bf0, acc[0][0]); acc[0][1] = MF(af0, bf1, acc[0][1]);
        acc[0][2] = MF(af0, bf2, acc[0][2]); acc[0][3] = MF(af0, bf3, acc[0][3]);
        acc[1][0] = MF(af1, bf0, acc[1][0]); acc[1][1] = MF(af1, bf1, acc[1][1]);
        acc[1][2] = MF(af1, bf2, acc[1][2]); acc[1][3] = MF(af1, bf3, acc[1][3]);
        __builtin_amdgcn_s_setprio(0);
        __builtin_amdgcn_s_barrier();

        // ---- phase 3: kk=1, m-half 1 (reuses B kk=1) | no stage ----
        af0 = *(const short8*)(base + aroB + 2 * 2048 + swz1);
        af1 = *(const short8*)(base + aroB + 3 * 2048 + swz1);
        __builtin_amdgcn_s_setprio(1);
        acc[2][0] = MF(af0, bf0, acc[2][0]); acc[2][1] = MF(af0, bf1, acc[2][1]);
        acc[2][2] = MF(af0, bf2, acc[2][2]); acc[2][3] = MF(af0, bf3, acc[2][3]);
        acc[3][0] = MF(af1, bf0, acc[3][0]); acc[3][1] = MF(af1, bf1, acc[3][1]);
        acc[3][2] = MF(af1, bf2, acc[3][2]); acc[3][3] = MF(af1, bf3, acc[3][3]);
        __builtin_amdgcn_s_setprio(0);
        // next iteration's start barrier closes this K-tile
    }

    // ---------------- epilogue (LDS reused after full drain) ----------------
    __syncthreads();
    ushort* epi = (ushort*)ldsb;
    int seg = n0 >= 1536 ? 2 : (n0 >= 768 ? 1 : 0);
    if (seg < 2) {
        float scale = (seg == 0) ? 0.125f : 1.0f;   // fold attention scale into Q
        for (int ni = 0; ni < 4; ni++) {
            int nl = wn * 64 + ni * 16 + l15;
            float bv = bias[n0 + nl];
            for (int mi = 0; mi < 4; mi++)
                for (int r = 0; r < 4; r++) {
                    int ml = wm * 64 + mi * 16 + quad * 4 + r;
                    epi[ml * 132 + nl] = f2bf((acc[mi][ni][r] + bv) * scale);
                }
        }
        __syncthreads();
        int row = tid >> 1, h2 = tid & 1;           // 512 threads, 256 rows
        size_t gm = (size_t)(m0 + row);
        for (int i = 0; i < 8; i++) {
            uint4 v = *(const uint4*)&epi[row * 132 + h2 * 64 + i * 8];
            *(uint4*)&QKb[gm * 1536 + n0 + h2 * 64 + i * 8] = v;
        }
    } else {
        for (int ni = 0; ni < 4; ni++) {
            int nl = wn * 64 + ni * 16 + l15;
            float bv = bias[n0 + nl];
            for (int mi = 0; mi < 4; mi++) {
                int ml = wm * 64 + mi * 16 + quad * 4;
                ushort4 p4;
                p4.x = f2bf(acc[mi][ni][0] + bv);
                p4.y = f2bf(acc[mi][ni][1] + bv);
                p4.z = f2bf(acc[mi][ni][2] + bv);
                p4.w = f2bf(acc[mi][ni][3] + bv);
                *(ushort4*)&epi[nl * 264 + ml] = p4;
            }
        }
        __syncthreads();
        int row = tid >> 2, q4 = tid & 3;           // 128 rows x 4 col-quarters
        int nn = n0 + row - 1536;
        int hh = nn >> 6, d = nn & 63;
        int bb = m0 >> 11, s0 = m0 & 2047;          // 256 | 2048 so bb uniform
        for (int i = 0; i < 8; i++) {
            uint4 v = *(const uint4*)&epi[row * 264 + q4 * 64 + i * 8];
            *(uint4*)&Vt[((size_t)(bb * NH + hh) * HD + d) * S_LEN + s0 + q4 * 64 + i * 8] = v;
        }
    }
}

// ---------------- Attention: ReLU(Q K^T, causal) @ V  (Q pre-scaled) --------
// Round-2 dataflow verbatim (proven 56.0 us): K+V staged in LDS, double-
// buffered, XOR-swizzled, one barrier/stage, PV via 16x16x32 + permlane
// repack. NEW: XCD-local schedule -- heads partitioned into 8 groups of 6;
// group g runs only on blocks with blockIdx%8==g (empirical XCD round-robin),
// so each XCD's L2 holds its 6 heads' K/V (3 MB < 4 MB) and staging becomes
// L2-hit instead of L3/HBM. 480 blocks = 8 x 60, all co-resident; per-group
// balance: 4 singles (qt 15..12) + 6 pairs (11+0,...,6+5), heavy-first.
__global__ __launch_bounds__(256, 2) void attn(const ushort* __restrict__ QKb,
                                               const ushort* __restrict__ Vt,
                                               float* __restrict__ out) {
    __shared__ ushort lds[32768];   // 64KB: K buffers @0/16384B; V @32768/49152B
    char* ldsb = (char*)lds;
    int tid = threadIdx.x;
    int w = tid >> 6, lane = tid & 63;
    int l15 = lane & 15, quad = lane >> 4;
    int r8 = lane >> 3, cc = lane & 7;
    int rr = lane >> 4;

    // ---- hoisted lane-dependent offsets (loop-invariant) ----
    int kfo[2];
    for (int ch = 0; ch < 2; ch++)
        kfo[ch] = l15 * 128 + ((ch * 4 + quad) ^ (l15 & 7)) * 16;
    // V b128 fragment offsets: 32-k tile T (0..3): d=ni*16+l15 row, slot T*4+quad
    int vfo2[4];
    for (int T = 0; T < 4; T++)
        vfo2[T] = 32768 + l15 * 256 + ((T * 4 + quad) ^ l15) * 16;
    int rhs[2] = { w * 32 + l15, w * 32 + 16 + l15 };   // causal threshold (qt cancels)
    int kgo = (w * 32 + r8) * 3072 + (cc ^ r8) * 16;    // K staging (QKb row = 3072 B)
    int vgo[4];
    for (int i = 0; i < 4; i++)
        vgo[i] = (w * 16 + i * 4 + rr) * 4096 + (((lane & 15) ^ ((i * 4 + rr) & 15)) * 16);
    int kst = (w * 32) * 128;            // LDS K dst, + i*1024 + p*16384
    int vst = 32768 + (w * 16) * 256;    // LDS V dst, + i*1024 + p*16384

    // ---- XCD-local schedule: 480 blocks = 8 groups x 60 ----
    int b = blockIdx.x;
    int g = b & 7;                 // XCD id (empirical blockIdx%8 round-robin)
    int idx = b >> 3;              // 0..59 within group
    int role = idx / 6;            // 0..9, heavy-first in dispatch order
    int bh = g * 6 + (idx % 6);    // this block's single (batch,head)
    int nit, qts[2];
    if (role < 4) { nit = 1; qts[0] = 15 - role; qts[1] = 0; }
    else          { nit = 2; qts[0] = 15 - role; qts[1] = role - 4; }
    int bg = bh / NH, h = bh % NH;

    const char* kg = (const char*)(QKb + (size_t)bg * S_LEN * 1536 + 768 + h * 64) + kgo;
    const char* vgb = (const char*)(Vt + (size_t)bh * HD * S_LEN);

    auto prefetch = [&](int st, int dstP) {
        const char* kbase = kg + (size_t)st * 393216;   // 128 k-rows x 3072 B
        const char* vbase = vgb + st * 256;             // 128 k-cols x 2 B
        for (int i = 0; i < 4; i++)
            gl_lds16(kbase + i * 24576, ldsb + dstP * 16384 + kst + i * 1024);
        for (int i = 0; i < 4; i++)
            gl_lds16(vbase + vgo[i], ldsb + dstP * 16384 + vst + i * 1024);
    };

    const ushort* Qcol = QKb + (size_t)bg * S_LEN * 1536 + h * 64;

    int p = 0;
    prefetch(0, 0);
    for (int ii = 0; ii < nit; ii++) {
        int qt = qts[ii];
        short8 qf[2][2];
        for (int nq = 0; nq < 2; nq++)
            for (int ch = 0; ch < 2; ch++)
                qf[nq][ch] = *(const short8*)(Qcol +
                    (size_t)(qt * 128 + w * 32 + nq * 16 + l15) * 1536 + ch * 32 + quad * 8);

        floatx4 acco[2][4] = {};
        int nst = qt + 1;
        for (int st = 0; st < nst; st++) {
            __syncthreads();                       // sole barrier: buf[p] staged; buf[p^1] free
            if (st + 1 < nst)
                prefetch(st + 1, p ^ 1);
            else if (ii + 1 < nit)
                prefetch(0, p ^ 1);                // next item's stage 0 (same bh)

            bool diag = (st == qt);
            const char* kb = ldsb + p * 16384;

            for (int jsub = 0; jsub < 2; jsub++) {
                // S^T = K·Q^T : 64 k-rows x 32 q, K(d)=64
                floatx4 stc[4][2] = {};
                for (int ch = 0; ch < 2; ch++) {
                    short8 kf[4];
                    for (int mk = 0; mk < 4; mk++)
                        kf[mk] = *(const short8*)(kb + kfo[ch] + jsub * 8192 + mk * 2048);
                    for (int mk = 0; mk < 4; mk++)
                        for (int nq = 0; nq < 2; nq++)
                            stc[mk][nq] = __builtin_amdgcn_mfma_f32_16x16x32_bf16(
                                kf[mk], qf[nq][ch], stc[mk][nq], 0, 0, 0);
                }

                // ReLU + causal mask + pack (k = quad*4 + r layout, 2 bf16/uint)
                unsigned int pk[4][2][2];
                for (int mk = 0; mk < 4; mk++) {
                    for (int nq = 0; nq < 2; nq++) {
                        float e[4];
                        for (int r = 0; r < 4; r++)
                            e[r] = fmaxf(stc[mk][nq][r], 0.0f);
                        if (diag) {
                            int kl = jsub * 64 + mk * 16 + quad * 4;
                            for (int r = 0; r < 4; r++)
                                if (kl + r > rhs[nq]) e[r] = 0.0f;
                        }
                        pk[mk][nq][0] = pack2bf(e[0], e[1]);
                        pk[mk][nq][1] = pack2bf(e[2], e[3]);
                    }
                }

                // O += P·V via 16x16x32: repack P cross-quad with permlane swaps
                for (int pr = 0; pr < 2; pr++) {
                    int T = jsub * 2 + pr;          // 32-k tile index within stage
                    short8 vf[4];
                    for (int ni = 0; ni < 4; ni++)
                        vf[ni] = *(const short8*)(kb + vfo2[T] + ni * 4096);
                    for (int mi = 0; mi < 2; mi++) {
                        unsigned int a0 = pk[2 * pr][mi][0], a1 = pk[2 * pr][mi][1];
                        unsigned int b0 = pk[2 * pr + 1][mi][0], b1 = pk[2 * pr + 1][mi][1];
                        pl32_swap(a0, b0);  pl32_swap(a1, b1);
                        pl16_swap(a0, b0);  pl16_swap(a1, b1);
                        // now: a0=k q*8+{0,1}, a1=+{2,3}, b0=+{4,5}, b1=+{6,7}
                        short8 af = __builtin_bit_cast(short8, (uint4v){a0, a1, b0, b1});
                        for (int ni = 0; ni < 4; ni++)
                            acco[mi][ni] = __builtin_amdgcn_mfma_f32_16x16x32_bf16(
                                af, vf[ni], acco[mi][ni], 0, 0, 0);
                    }
                }
            }
            p ^= 1;
        }

        // epilogue: out[b][s][h*64+d] fp32 (overlaps next item's prefetch)
        for (int mi = 0; mi < 2; mi++) {
            for (int ni = 0; ni < 4; ni++) {
                int d = ni * 16 + l15;
                for (int r = 0; r < 4; r++) {
                    int s = qt * 128 + w * 32 + mi * 16 + quad * 4 + r;
                    out[((size_t)bg * S_LEN + s) * EMB + h * 64 + d] = acco[mi][ni][r];
                }
            }
        }
    }
}

extern "C" void kernel_launch(void* const* d_in, const int* in_sizes, int n_in,
                              void* d_out, int out_size, void* d_ws, size_t ws_size,
                              hipStream_t stream) {
    const float* x    = (const float*)d_in[0];   // [4,2048,768]
    const float* W    = (const float*)d_in[1];   // [768,2304]
    const float* bias = (const float*)d_in[2];   // [2304]
    float* out = (float*)d_out;                  // [4,2048,768] fp32

    char* ws = (char*)d_ws;
    const size_t SZ_X  = (size_t)8192 * EMB * 2;
    const size_t SZ_W  = (size_t)E3 * EMB * 2;
    const size_t SZ_QK = (size_t)8192 * 1536 * 2;
    ushort* Xb  = (ushort*)(ws);
    ushort* Wt  = (ushort*)(ws + SZ_X);
    ushort* QKb = (ushort*)(ws + SZ_X + SZ_W);
    ushort* Vt  = (ushort*)(ws + SZ_X + SZ_W + SZ_QK);

    static bool attr_done = false;
    if (!attr_done) {
        hipFuncSetAttribute((const void*)qkv_gemm,
                            hipFuncAttributeMaxDynamicSharedMemorySize, 147456);
        attr_done = true;
    }

    conv_fused<<<dim3(6144 + 1728), dim3(256), 0, stream>>>(x, Xb, W, Wt);
    qkv_gemm<<<dim3(32, 18), dim3(512), 147456, stream>>>(Xb, Wt, bias, QKb, Vt);
    attn<<<dim3(480), dim3(256), 0, stream>>>(QKb, Vt, out);
}